// Round 4
// baseline (903.404 us; speedup 1.0000x reference)
//
#include <hip/hip_runtime.h>

// Problem sizes
#define NROWS 8192   // B*T
#define MCB   1024   // codebook size M
#define DD    256    // feature dim D
#define TT    128    // T
#define BB    64     // B

// ws offsets (in floats)
#define OFF_DA      0ul
#define OFF_DV      8388608ul
#define OFF_XX_A    16777216ul
#define OFF_XX_V    16785408ul
#define OFF_EE      16793600ul
#define OFF_SMIN_A  16794624ul
#define OFF_LZ1_A   16802816ul
#define OFF_IZ2_A   16811008ul
#define OFF_IDX_A   16819200ul
#define OFF_SMIN_V  16827392ul
#define OFF_LZ1_V   16835584ul
#define OFF_IZ2_V   16843776ul
#define OFF_IDX_V   16851968ul
#define OFF_S1      16860160ul
#define OFF_S2      17384448ul
#define OFF_PART    17908736ul
#define OFF_MAX     17908992ul
#define OFF_PACC    17909000ul   // 256 doubles, per-block loss partials

// ---------------------------------------------------------------------------
__device__ __forceinline__ void gload_lds16(const float* gsrc, float* ldst) {
  __builtin_amdgcn_global_load_lds(
      (const __attribute__((address_space(1))) void*)gsrc,
      (__attribute__((address_space(3))) void*)ldst, 16, 0, 0);
}

// ---------------------------------------------------------------------------
// Kernel 1: row sums of squares (fp64 accumulate for accuracy)
__global__ void k_sumsq(const float* __restrict__ A, const float* __restrict__ V,
                        const float* __restrict__ E, float* __restrict__ ws) {
  const int lane = threadIdx.x & 63;
  const int wid  = threadIdx.x >> 6;
  const int row = blockIdx.x * 4 + wid;   // 0..17407
  const float* src; float* dst; int r;
  if (row < 8192)       { src = A; r = row;         dst = ws + OFF_XX_A; }
  else if (row < 16384) { src = V; r = row - 8192;  dst = ws + OFF_XX_V; }
  else                  { src = E; r = row - 16384; dst = ws + OFF_EE; }
  float4 x = *(const float4*)(src + (size_t)r * DD + lane * 4);
  double acc = (double)x.x * x.x + (double)x.y * x.y +
               (double)x.z * x.z + (double)x.w * x.w;
  #pragma unroll
  for (int off = 32; off; off >>= 1) acc += __shfl_xor(acc, off);
  if (lane == 0) dst[r] = (float)acc;
}

// ---------------------------------------------------------------------------
// Kernel 2: dist GEMM. d[n,m] = (ee[m] + xx[n]) - 2 * (x[n,:] . e[m,:])
// 64x64 C-tile, 4x4/thread, K-chunk 32, double-buffered global_load_lds
// staging (T3 minimal 2-phase: stage next || compute current, 1 barrier/chunk).
// LDS layout [r][32] row-major (forced by linear global_load_lds dest).
__global__ __launch_bounds__(256) void k_dist(const float* __restrict__ A,
    const float* __restrict__ V, const float* __restrict__ E,
    float* __restrict__ ws) {
  const int z = blockIdx.z;
  const float* X  = z ? V : A;
  const float* xx = ws + (z ? OFF_XX_V : OFF_XX_A);
  const float* ee = ws + OFF_EE;
  float* Dst = ws + (z ? OFF_DV : OFF_DA);

  __shared__ __align__(16) float As[2][64 * 32];
  __shared__ __align__(16) float Bs[2][64 * 32];

  const int tid = threadIdx.x;
  const int tx = tid & 15;          // col group: cols tx*4..tx*4+3
  const int ty = tid >> 4;          // row group: rows ty*4..ty*4+3

  // chunked XCD swizzle (2048 blocks per z, 2048%8==0 -> bijective):
  // consecutive swizzled ids share the same row-block (A-tile) on one XCD.
  const int bid = blockIdx.y * 16 + blockIdx.x;       // 0..2047
  const int sw  = (bid & 7) * 256 + (bid >> 3);
  const int colb = sw & 15, rowb = sw >> 4;
  const int row0 = rowb * 64;
  const int col0 = colb * 64;

  // staging addresses for this thread: 2 chunks of A + 2 of B per K-chunk
  const int r0 = tid >> 3;          // 0..31   (round 0 row)
  const int q4 = (tid & 7) * 4;     // k offset 0..28
  const float* gA0 = X + (size_t)(row0 + r0) * DD + q4;
  const float* gA1 = X + (size_t)(row0 + 32 + r0) * DD + q4;
  const float* gB0 = E + (size_t)(col0 + r0) * DD + q4;
  const float* gB1 = E + (size_t)(col0 + 32 + r0) * DD + q4;
  const int ldso = tid * 4;         // float offset of this thread's 16B chunk

  float acc[4][4] = {};

  // prologue: stage chunk 0 into buf 0
  gload_lds16(gA0, &As[0][ldso]);
  gload_lds16(gA1, &As[0][1024 + ldso]);
  gload_lds16(gB0, &Bs[0][ldso]);
  gload_lds16(gB1, &Bs[0][1024 + ldso]);
  __syncthreads();   // drains vmcnt -> buf0 ready

  #pragma unroll
  for (int t = 0; t < 8; ++t) {
    const int cur = t & 1;
    if (t < 7) {
      const int kc = (t + 1) * 32;
      gload_lds16(gA0 + kc, &As[cur ^ 1][ldso]);
      gload_lds16(gA1 + kc, &As[cur ^ 1][1024 + ldso]);
      gload_lds16(gB0 + kc, &Bs[cur ^ 1][ldso]);
      gload_lds16(gB1 + kc, &Bs[cur ^ 1][1024 + ldso]);
    }
    #pragma unroll
    for (int k4 = 0; k4 < 32; k4 += 4) {
      float4 a[4], b[4];
      #pragma unroll
      for (int i = 0; i < 4; ++i)
        a[i] = *(const float4*)(&As[cur][(ty * 4 + i) * 32 + k4]);
      #pragma unroll
      for (int j = 0; j < 4; ++j)
        b[j] = *(const float4*)(&Bs[cur][(tx * 4 + j) * 32 + k4]);
      #pragma unroll
      for (int i = 0; i < 4; ++i)
        #pragma unroll
        for (int j = 0; j < 4; ++j) {
          acc[i][j] = fmaf(a[i].x, b[j].x, acc[i][j]);
          acc[i][j] = fmaf(a[i].y, b[j].y, acc[i][j]);
          acc[i][j] = fmaf(a[i].z, b[j].z, acc[i][j]);
          acc[i][j] = fmaf(a[i].w, b[j].w, acc[i][j]);
        }
    }
    __syncthreads();  // drains vmcnt (next buf landed) + all waves done reading cur
  }

  float er[4];
  #pragma unroll
  for (int j = 0; j < 4; ++j) er[j] = ee[col0 + tx * 4 + j];
  #pragma unroll
  for (int i = 0; i < 4; ++i) {
    float xri = xx[row0 + ty * 4 + i];
    float4 o;
    o.x = (er[0] + xri) - 2.0f * acc[i][0];
    o.y = (er[1] + xri) - 2.0f * acc[i][1];
    o.z = (er[2] + xri) - 2.0f * acc[i][2];
    o.w = (er[3] + xri) - 2.0f * acc[i][3];
    *(float4*)(Dst + (size_t)(row0 + ty * 4 + i) * MCB + col0 + tx * 4) = o;
  }
}

// ---------------------------------------------------------------------------
// Kernel 3: per-row stats (min/argmin, softmax denominators) + quantize write.
__global__ void k_rowstats(const float* __restrict__ A, const float* __restrict__ V,
                           const float* __restrict__ E, float* __restrict__ ws,
                           float* __restrict__ out) {
  const int z = blockIdx.y;
  const float* Dm = ws + (z ? OFF_DV : OFF_DA);
  const float* X  = z ? V : A;
  float* smin_o = ws + (z ? OFF_SMIN_V : OFF_SMIN_A);
  float* lz1_o  = ws + (z ? OFF_LZ1_V  : OFF_LZ1_A);
  float* iz2_o  = ws + (z ? OFF_IZ2_V  : OFF_IZ2_A);
  int*   idx_o  = (int*)(ws + (z ? OFF_IDX_V : OFF_IDX_A));
  float* qout = out + 1 + (size_t)z * ((size_t)NROWS * DD);

  const int lane = threadIdx.x & 63, wid = threadIdx.x >> 6;
  const int n = blockIdx.x * 4 + wid;
  const float* drow = Dm + (size_t)n * MCB;

  float v[16];
  #pragma unroll
  for (int c = 0; c < 4; ++c) {
    float4 t = *(const float4*)(drow + c * 256 + lane * 4);
    v[c*4+0] = t.x; v[c*4+1] = t.y; v[c*4+2] = t.z; v[c*4+3] = t.w;
  }
  float bv = 3.4e38f; int bi = 0;
  #pragma unroll
  for (int c = 0; c < 4; ++c)
    #pragma unroll
    for (int j = 0; j < 4; ++j) {
      float val = v[c*4+j];
      int m = c * 256 + lane * 4 + j;
      if (val < bv) { bv = val; bi = m; }
    }
  #pragma unroll
  for (int off = 32; off; off >>= 1) {
    float ov = __shfl_xor(bv, off);
    int   oi = __shfl_xor(bi, off);
    if (ov < bv || (ov == bv && oi < bi)) { bv = ov; bi = oi; }
  }
  float smin = sqrtf(fmaxf(bv, 0.0f));
  float z1 = 0.f, z2 = 0.f;
  #pragma unroll
  for (int q = 0; q < 16; ++q) {
    float w = sqrtf(fmaxf(v[q], 0.0f)) - smin;
    z1 += expf(-w);
    z2 += expf(-2.0f * w);
  }
  #pragma unroll
  for (int off = 32; off; off >>= 1) {
    z1 += __shfl_xor(z1, off);
    z2 += __shfl_xor(z2, off);
  }
  if (lane == 0) {
    smin_o[n] = smin;
    lz1_o[n]  = logf(z1);
    iz2_o[n]  = 1.0f / z2;
    idx_o[n]  = bi;
  }
  const float* erow = E + (size_t)bi * DD;
  const float* xrow = X + (size_t)n * DD;
  #pragma unroll
  for (int p = 0; p < 4; ++p) {
    int d0 = p * 64 + lane;
    float xv = xrow[d0];
    float ev = erow[d0];
    qout[(size_t)n * DD + d0] = xv + (ev - xv);
  }
}

// ---------------------------------------------------------------------------
// Kernel 4: S[t,b,c] = sum_m adj_p[b*T+t, m] * logq[c*T+t, m]
__global__ __launch_bounds__(256) void k_sgemm(float* __restrict__ ws) {
  const int z = blockIdx.y;
  const int t = blockIdx.x;
  const float* Dp = ws + (z ? OFF_DV : OFF_DA);
  const float* Dq = ws + (z ? OFF_DA : OFF_DV);
  const float* smin_p = ws + (z ? OFF_SMIN_V : OFF_SMIN_A);
  const float* iz2_p  = ws + (z ? OFF_IZ2_V  : OFF_IZ2_A);
  const float* smin_q = ws + (z ? OFF_SMIN_A : OFF_SMIN_V);
  const float* lz1_q  = ws + (z ? OFF_LZ1_A  : OFF_LZ1_V);
  float* S = ws + (z ? OFF_S2 : OFF_S1);

  __shared__ __align__(16) float PA[64][68];
  __shared__ __align__(16) float LQ[64][68];
  __shared__ float sP[64], izP[64], sQ[64], lzQ[64];

  const int tid = threadIdx.x;
  const int tx = tid & 15, ty = tid >> 4;
  const int lm = tid & 63, wq = tid >> 6;

  if (tid < 64) {
    size_t n = (size_t)tid * TT + t;
    sP[tid] = smin_p[n]; izP[tid] = iz2_p[n];
    sQ[tid] = smin_q[n]; lzQ[tid] = lz1_q[n];
  }
  __syncthreads();

  float acc[4][4] = {};
  for (int mc = 0; mc < MCB; mc += 64) {
    #pragma unroll
    for (int i = 0; i < 16; ++i) {
      int b = i * 4 + wq;
      size_t n = (size_t)b * TT + t;
      float dp = Dp[n * MCB + mc + lm];
      float wp = sqrtf(fmaxf(dp, 0.f)) - sP[b];
      PA[lm][b] = expf(-2.f * wp) * izP[b];
      float dq = Dq[n * MCB + mc + lm];
      float wv = sqrtf(fmaxf(dq, 0.f)) - sQ[b];
      LQ[lm][b] = -wv - lzQ[b];
    }
    __syncthreads();
    #pragma unroll
    for (int mm = 0; mm < 64; ++mm) {
      float4 av = *(const float4*)(&PA[mm][ty << 2]);
      float4 bv = *(const float4*)(&LQ[mm][tx << 2]);
      float aa[4] = {av.x, av.y, av.z, av.w};
      float bb[4] = {bv.x, bv.y, bv.z, bv.w};
      #pragma unroll
      for (int i = 0; i < 4; ++i)
        #pragma unroll
        for (int j = 0; j < 4; ++j)
          acc[i][j] = fmaf(aa[i], bb[j], acc[i][j]);
    }
    __syncthreads();
  }
  #pragma unroll
  for (int i = 0; i < 4; ++i) {
    float4 o = {acc[i][0], acc[i][1], acc[i][2], acc[i][3]};
    *(float4*)(S + ((size_t)t * 64 + (ty << 2) + i) * 64 + (tx << 2)) = o;
  }
}

// ---------------------------------------------------------------------------
// Kernel 5a: partial min over S1/S2
__global__ void k_smin(float* __restrict__ ws) {
  const float* S = ws + (blockIdx.y ? OFF_S2 : OFF_S1);
  float* part = ws + OFF_PART;
  size_t base = (size_t)blockIdx.x * 4096;
  float m = 3.4e38f;
  for (int i = threadIdx.x; i < 4096; i += 256) m = fminf(m, S[base + i]);
  #pragma unroll
  for (int off = 32; off; off >>= 1) m = fminf(m, __shfl_xor(m, off));
  __shared__ float red[4];
  const int lane = threadIdx.x & 63, wid = threadIdx.x >> 6;
  if (lane == 0) red[wid] = m;
  __syncthreads();
  if (threadIdx.x == 0)
    part[blockIdx.y * 128 + blockIdx.x] =
        fminf(fminf(red[0], red[1]), fminf(red[2], red[3]));
}

// Kernel 5b: final max(-S) per tensor
__global__ void k_sfinal(float* __restrict__ ws) {
  const float* part = ws + OFF_PART;
  float* maxv = ws + OFF_MAX;
  const int tens = threadIdx.x >> 7;
  const int i = threadIdx.x & 127;
  float m = part[tens * 128 + i];
  #pragma unroll
  for (int off = 32; off; off >>= 1) m = fminf(m, __shfl_xor(m, off));
  __shared__ float red[4];
  const int lane = threadIdx.x & 63, wid = threadIdx.x >> 6;
  if (lane == 0) red[wid] = m;
  __syncthreads();
  if (threadIdx.x == 0)   maxv[0] = -fminf(red[0], red[1]);
  if (threadIdx.x == 128) maxv[1] = -fminf(red[2], red[3]);
}

// ---------------------------------------------------------------------------
// Kernel 6: loss rows; per-wave register accumulation, per-block partial.
__global__ __launch_bounds__(256) void k_loss(float* __restrict__ ws) {
  const int lane = threadIdx.x & 63, wid = threadIdx.x >> 6;
  const int wglobal = blockIdx.x * 4 + wid;   // 0..1023
  const float* Smax = ws + OFF_MAX;
  double acc = 0.0;
  #pragma unroll 4
  for (int r = 0; r < 16; ++r) {
    int gw = wglobal * 16 + r;                // 0..16383
    int tens = gw >> 13;
    int rem = gw & 8191;                      // t*64 + b
    const float* S = ws + (tens ? OFF_S2 : OFF_S1);
    float maxv = Smax[tens];
    float ev = expf(S[(size_t)rem * 64 + lane] + maxv);
    float sum = ev;
    #pragma unroll
    for (int off = 32; off; off >>= 1) sum += __shfl_xor(sum, off);
    float diag = __shfl(ev, rem & 63);
    if (lane == 0) acc += (double)logf(diag / (sum + 1e-5f));
  }
  __shared__ double red[4];
  if (lane == 0) red[wid] = acc;
  __syncthreads();
  if (threadIdx.x == 0)
    ((double*)(ws + OFF_PACC))[blockIdx.x] = red[0] + red[1] + red[2] + red[3];
}

// Kernel 7: reduce 256 per-block partials, finalize loss
__global__ void k_fin(const float* __restrict__ ws, float* __restrict__ out) {
  const double* p = (const double*)(ws + OFF_PACC);
  const int lane = threadIdx.x & 63, wid = threadIdx.x >> 6;
  double v = p[threadIdx.x];
  #pragma unroll
  for (int off = 32; off; off >>= 1) v += __shfl_xor(v, off);
  __shared__ double red[4];
  if (lane == 0) red[wid] = v;
  __syncthreads();
  if (threadIdx.x == 0)
    out[0] = (float)(-(red[0] + red[1] + red[2] + red[3]) / 16384.0);
}

// ---------------------------------------------------------------------------
extern "C" void kernel_launch(void* const* d_in, const int* in_sizes, int n_in,
                              void* d_out, int out_size, void* d_ws, size_t ws_size,
                              hipStream_t stream) {
  const float* A = (const float*)d_in[0];
  const float* V = (const float*)d_in[1];
  const float* E = (const float*)d_in[2];
  float* out = (float*)d_out;
  float* ws  = (float*)d_ws;

  k_sumsq  <<<dim3(4352), dim3(256), 0, stream>>>(A, V, E, ws);
  k_dist   <<<dim3(16, 128, 2), dim3(256), 0, stream>>>(A, V, E, ws);
  k_rowstats<<<dim3(2048, 2), dim3(256), 0, stream>>>(A, V, E, ws, out);
  k_sgemm  <<<dim3(128, 2), dim3(256), 0, stream>>>(ws);
  k_smin   <<<dim3(128, 2), dim3(256), 0, stream>>>(ws);
  k_sfinal <<<dim3(1), dim3(256), 0, stream>>>(ws);
  k_loss   <<<dim3(256), dim3(256), 0, stream>>>(ws);
  k_fin    <<<dim3(1), dim3(256), 0, stream>>>(ws, out);
}

// Round 5
// 255.701 us; speedup vs baseline: 3.5330x; 3.5330x over previous
//
#include <hip/hip_runtime.h>

// Problem sizes
#define NROWS 8192   // B*T
#define MCB   1024   // codebook size M
#define DD    256    // feature dim D
#define TT    128    // T
#define BB    64     // B

// ws offsets (in floats)
#define OFF_DA      0ul
#define OFF_DV      8388608ul
#define OFF_XX_A    16777216ul
#define OFF_XX_V    16785408ul
#define OFF_EE      16793600ul
#define OFF_SMIN_A  16794624ul
#define OFF_LZ1_A   16802816ul
#define OFF_IZ2_A   16811008ul
#define OFF_IDX_A   16819200ul
#define OFF_SMIN_V  16827392ul
#define OFF_LZ1_V   16835584ul
#define OFF_IZ2_V   16843776ul
#define OFF_IDX_V   16851968ul
#define OFF_S1      16860160ul
#define OFF_S2      17384448ul
#define OFF_PART    17908736ul
#define OFF_MAX     17908992ul
#define OFF_PACC    17909000ul   // 256 doubles, per-block loss partials

// ---------------------------------------------------------------------------
__device__ __forceinline__ void gload_lds16(const float* gsrc, float* ldst) {
  __builtin_amdgcn_global_load_lds(
      (const __attribute__((address_space(1))) void*)gsrc,
      (__attribute__((address_space(3))) void*)ldst, 16, 0, 0);
}

// ---------------------------------------------------------------------------
// Kernel 1: row sums of squares (fp64 accumulate for accuracy)
__global__ void k_sumsq(const float* __restrict__ A, const float* __restrict__ V,
                        const float* __restrict__ E, float* __restrict__ ws) {
  const int lane = threadIdx.x & 63;
  const int wid  = threadIdx.x >> 6;
  const int row = blockIdx.x * 4 + wid;   // 0..17407
  const float* src; float* dst; int r;
  if (row < 8192)       { src = A; r = row;         dst = ws + OFF_XX_A; }
  else if (row < 16384) { src = V; r = row - 8192;  dst = ws + OFF_XX_V; }
  else                  { src = E; r = row - 16384; dst = ws + OFF_EE; }
  float4 x = *(const float4*)(src + (size_t)r * DD + lane * 4);
  double acc = (double)x.x * x.x + (double)x.y * x.y +
               (double)x.z * x.z + (double)x.w * x.w;
  #pragma unroll
  for (int off = 32; off; off >>= 1) acc += __shfl_xor(acc, off);
  if (lane == 0) dst[r] = (float)acc;
}

// ---------------------------------------------------------------------------
// Kernel 2: dist GEMM. d[n,m] = (ee[m] + xx[n]) - 2 * (x[n,:] . e[m,:])
// 64x64 C-tile, 4x4/thread, K-chunk 32, double-buffered global_load_lds.
// T2 XOR swizzle (both-sides): LDS tile [64 rows][8 chunks of 16B];
// physical chunk pc of row r holds logical chunk pc ^ ((r>>2)&7).
//  - stage: lane L (writes linearly to byte L*16 = row L>>3, chunk L&7)
//    fetches GLOBAL chunk (L&7) ^ ((L>>5)&7)   [(row>>2)&7 = (L>>5)&7]
//  - read:  float idx = row*32 + (k4 ^ (((row>>2)&7)<<2))
// B-read rows {4*tx+j}: chunks (k4/4)^(tx&7) -> 8 quads x 2 lanes = 2-way, free.
__global__ __launch_bounds__(256) void k_dist(const float* __restrict__ A,
    const float* __restrict__ V, const float* __restrict__ E,
    float* __restrict__ ws) {
  const int z = blockIdx.z;
  const float* X  = z ? V : A;
  const float* xx = ws + (z ? OFF_XX_V : OFF_XX_A);
  const float* ee = ws + OFF_EE;
  float* Dst = ws + (z ? OFF_DV : OFF_DA);

  __shared__ __align__(16) float As[2][64 * 32];
  __shared__ __align__(16) float Bs[2][64 * 32];

  const int tid = threadIdx.x;
  const int tx = tid & 15;          // col group: cols tx*4..tx*4+3
  const int ty = tid >> 4;          // row group: rows ty*4..ty*4+3

  // chunked XCD swizzle (2048 blocks per z, bijective)
  const int bid = blockIdx.y * 16 + blockIdx.x;       // 0..2047
  const int sw  = (bid & 7) * 256 + (bid >> 3);
  const int colb = sw & 15, rowb = sw >> 4;
  const int row0 = rowb * 64;
  const int col0 = colb * 64;

  // staging: lane fetches the SWIZZLED global k-chunk
  const int r0  = tid >> 3;                         // 0..31
  const int ksw = (((tid & 7) ^ ((tid >> 5) & 7)) << 2);  // swizzled k-offset
  const float* gA0 = X + (size_t)(row0 + r0) * DD + ksw;
  const float* gA1 = X + (size_t)(row0 + 32 + r0) * DD + ksw;
  const float* gB0 = E + (size_t)(col0 + r0) * DD + ksw;
  const float* gB1 = E + (size_t)(col0 + 32 + r0) * DD + ksw;
  const int ldso = tid * 4;         // linear dest (float offset)

  // per-thread read swizzle constants
  const int xa = (ty & 7) << 2;     // A rows ty*4+i: ((row>>2)&7)<<2 = (ty&7)<<2
  const int xb = (tx & 7) << 2;     // B rows tx*4+j

  float acc[4][4] = {};

  gload_lds16(gA0, &As[0][ldso]);
  gload_lds16(gA1, &As[0][1024 + ldso]);
  gload_lds16(gB0, &Bs[0][ldso]);
  gload_lds16(gB1, &Bs[0][1024 + ldso]);
  __syncthreads();

  #pragma unroll
  for (int t = 0; t < 8; ++t) {
    const int cur = t & 1;
    if (t < 7) {
      const int kc = (t + 1) * 32;
      gload_lds16(gA0 + kc, &As[cur ^ 1][ldso]);
      gload_lds16(gA1 + kc, &As[cur ^ 1][1024 + ldso]);
      gload_lds16(gB0 + kc, &Bs[cur ^ 1][ldso]);
      gload_lds16(gB1 + kc, &Bs[cur ^ 1][1024 + ldso]);
    }
    #pragma unroll
    for (int k4 = 0; k4 < 32; k4 += 4) {
      float4 a[4], b[4];
      #pragma unroll
      for (int i = 0; i < 4; ++i)
        a[i] = *(const float4*)(&As[cur][(ty * 4 + i) * 32 + (k4 ^ xa)]);
      #pragma unroll
      for (int j = 0; j < 4; ++j)
        b[j] = *(const float4*)(&Bs[cur][(tx * 4 + j) * 32 + (k4 ^ xb)]);
      #pragma unroll
      for (int i = 0; i < 4; ++i)
        #pragma unroll
        for (int j = 0; j < 4; ++j) {
          acc[i][j] = fmaf(a[i].x, b[j].x, acc[i][j]);
          acc[i][j] = fmaf(a[i].y, b[j].y, acc[i][j]);
          acc[i][j] = fmaf(a[i].z, b[j].z, acc[i][j]);
          acc[i][j] = fmaf(a[i].w, b[j].w, acc[i][j]);
        }
    }
    __syncthreads();
  }

  float er[4];
  #pragma unroll
  for (int j = 0; j < 4; ++j) er[j] = ee[col0 + tx * 4 + j];
  #pragma unroll
  for (int i = 0; i < 4; ++i) {
    float xri = xx[row0 + ty * 4 + i];
    float4 o;
    o.x = (er[0] + xri) - 2.0f * acc[i][0];
    o.y = (er[1] + xri) - 2.0f * acc[i][1];
    o.z = (er[2] + xri) - 2.0f * acc[i][2];
    o.w = (er[3] + xri) - 2.0f * acc[i][3];
    *(float4*)(Dst + (size_t)(row0 + ty * 4 + i) * MCB + col0 + tx * 4) = o;
  }
}

// ---------------------------------------------------------------------------
// Kernel 3: per-row stats (min/argmin, softmax denominators) + quantize write.
__global__ void k_rowstats(const float* __restrict__ A, const float* __restrict__ V,
                           const float* __restrict__ E, float* __restrict__ ws,
                           float* __restrict__ out) {
  const int z = blockIdx.y;
  const float* Dm = ws + (z ? OFF_DV : OFF_DA);
  const float* X  = z ? V : A;
  float* smin_o = ws + (z ? OFF_SMIN_V : OFF_SMIN_A);
  float* lz1_o  = ws + (z ? OFF_LZ1_V  : OFF_LZ1_A);
  float* iz2_o  = ws + (z ? OFF_IZ2_V  : OFF_IZ2_A);
  int*   idx_o  = (int*)(ws + (z ? OFF_IDX_V : OFF_IDX_A));
  float* qout = out + 1 + (size_t)z * ((size_t)NROWS * DD);

  const int lane = threadIdx.x & 63, wid = threadIdx.x >> 6;
  const int n = blockIdx.x * 4 + wid;
  const float* drow = Dm + (size_t)n * MCB;

  float v[16];
  #pragma unroll
  for (int c = 0; c < 4; ++c) {
    float4 t = *(const float4*)(drow + c * 256 + lane * 4);
    v[c*4+0] = t.x; v[c*4+1] = t.y; v[c*4+2] = t.z; v[c*4+3] = t.w;
  }
  float bv = 3.4e38f; int bi = 0;
  #pragma unroll
  for (int c = 0; c < 4; ++c)
    #pragma unroll
    for (int j = 0; j < 4; ++j) {
      float val = v[c*4+j];
      int m = c * 256 + lane * 4 + j;
      if (val < bv) { bv = val; bi = m; }
    }
  #pragma unroll
  for (int off = 32; off; off >>= 1) {
    float ov = __shfl_xor(bv, off);
    int   oi = __shfl_xor(bi, off);
    if (ov < bv || (ov == bv && oi < bi)) { bv = ov; bi = oi; }
  }
  float smin = sqrtf(fmaxf(bv, 0.0f));
  float z1 = 0.f, z2 = 0.f;
  #pragma unroll
  for (int q = 0; q < 16; ++q) {
    float w = sqrtf(fmaxf(v[q], 0.0f)) - smin;
    z1 += expf(-w);
    z2 += expf(-2.0f * w);
  }
  #pragma unroll
  for (int off = 32; off; off >>= 1) {
    z1 += __shfl_xor(z1, off);
    z2 += __shfl_xor(z2, off);
  }
  if (lane == 0) {
    smin_o[n] = smin;
    lz1_o[n]  = logf(z1);
    iz2_o[n]  = 1.0f / z2;
    idx_o[n]  = bi;
  }
  const float* erow = E + (size_t)bi * DD;
  const float* xrow = X + (size_t)n * DD;
  #pragma unroll
  for (int p = 0; p < 4; ++p) {
    int d0 = p * 64 + lane;
    float xv = xrow[d0];
    float ev = erow[d0];
    qout[(size_t)n * DD + d0] = xv + (ev - xv);
  }
}

// ---------------------------------------------------------------------------
// Kernel 4: S[t,b,c] = sum_m adj_p[b*T+t, m] * logq[c*T+t, m]
__global__ __launch_bounds__(256) void k_sgemm(float* __restrict__ ws) {
  const int z = blockIdx.y;
  const int t = blockIdx.x;
  const float* Dp = ws + (z ? OFF_DV : OFF_DA);
  const float* Dq = ws + (z ? OFF_DA : OFF_DV);
  const float* smin_p = ws + (z ? OFF_SMIN_V : OFF_SMIN_A);
  const float* iz2_p  = ws + (z ? OFF_IZ2_V  : OFF_IZ2_A);
  const float* smin_q = ws + (z ? OFF_SMIN_A : OFF_SMIN_V);
  const float* lz1_q  = ws + (z ? OFF_LZ1_A  : OFF_LZ1_V);
  float* S = ws + (z ? OFF_S2 : OFF_S1);

  __shared__ __align__(16) float PA[64][68];
  __shared__ __align__(16) float LQ[64][68];
  __shared__ float sP[64], izP[64], sQ[64], lzQ[64];

  const int tid = threadIdx.x;
  const int tx = tid & 15, ty = tid >> 4;
  const int lm = tid & 63, wq = tid >> 6;

  if (tid < 64) {
    size_t n = (size_t)tid * TT + t;
    sP[tid] = smin_p[n]; izP[tid] = iz2_p[n];
    sQ[tid] = smin_q[n]; lzQ[tid] = lz1_q[n];
  }
  __syncthreads();

  float acc[4][4] = {};
  for (int mc = 0; mc < MCB; mc += 64) {
    #pragma unroll
    for (int i = 0; i < 16; ++i) {
      int b = i * 4 + wq;
      size_t n = (size_t)b * TT + t;
      float dp = Dp[n * MCB + mc + lm];
      float wp = sqrtf(fmaxf(dp, 0.f)) - sP[b];
      PA[lm][b] = expf(-2.f * wp) * izP[b];
      float dq = Dq[n * MCB + mc + lm];
      float wv = sqrtf(fmaxf(dq, 0.f)) - sQ[b];
      LQ[lm][b] = -wv - lzQ[b];
    }
    __syncthreads();
    #pragma unroll
    for (int mm = 0; mm < 64; ++mm) {
      float4 av = *(const float4*)(&PA[mm][ty << 2]);
      float4 bv = *(const float4*)(&LQ[mm][tx << 2]);
      float aa[4] = {av.x, av.y, av.z, av.w};
      float bb[4] = {bv.x, bv.y, bv.z, bv.w};
      #pragma unroll
      for (int i = 0; i < 4; ++i)
        #pragma unroll
        for (int j = 0; j < 4; ++j)
          acc[i][j] = fmaf(aa[i], bb[j], acc[i][j]);
    }
    __syncthreads();
  }
  #pragma unroll
  for (int i = 0; i < 4; ++i) {
    float4 o = {acc[i][0], acc[i][1], acc[i][2], acc[i][3]};
    *(float4*)(S + ((size_t)t * 64 + (ty << 2) + i) * 64 + (tx << 2)) = o;
  }
}

// ---------------------------------------------------------------------------
// Kernel 5a: partial min over S1/S2
__global__ void k_smin(float* __restrict__ ws) {
  const float* S = ws + (blockIdx.y ? OFF_S2 : OFF_S1);
  float* part = ws + OFF_PART;
  size_t base = (size_t)blockIdx.x * 4096;
  float m = 3.4e38f;
  for (int i = threadIdx.x; i < 4096; i += 256) m = fminf(m, S[base + i]);
  #pragma unroll
  for (int off = 32; off; off >>= 1) m = fminf(m, __shfl_xor(m, off));
  __shared__ float red[4];
  const int lane = threadIdx.x & 63, wid = threadIdx.x >> 6;
  if (lane == 0) red[wid] = m;
  __syncthreads();
  if (threadIdx.x == 0)
    part[blockIdx.y * 128 + blockIdx.x] =
        fminf(fminf(red[0], red[1]), fminf(red[2], red[3]));
}

// Kernel 5b: final max(-S) per tensor
__global__ void k_sfinal(float* __restrict__ ws) {
  const float* part = ws + OFF_PART;
  float* maxv = ws + OFF_MAX;
  const int tens = threadIdx.x >> 7;
  const int i = threadIdx.x & 127;
  float m = part[tens * 128 + i];
  #pragma unroll
  for (int off = 32; off; off >>= 1) m = fminf(m, __shfl_xor(m, off));
  __shared__ float red[4];
  const int lane = threadIdx.x & 63, wid = threadIdx.x >> 6;
  if (lane == 0) red[wid] = m;
  __syncthreads();
  if (threadIdx.x == 0)   maxv[0] = -fminf(red[0], red[1]);
  if (threadIdx.x == 128) maxv[1] = -fminf(red[2], red[3]);
}

// ---------------------------------------------------------------------------
// Kernel 6: loss rows; per-wave register accumulation, per-block partial.
__global__ __launch_bounds__(256) void k_loss(float* __restrict__ ws) {
  const int lane = threadIdx.x & 63, wid = threadIdx.x >> 6;
  const int wglobal = blockIdx.x * 4 + wid;   // 0..1023
  const float* Smax = ws + OFF_MAX;
  double acc = 0.0;
  #pragma unroll 4
  for (int r = 0; r < 16; ++r) {
    int gw = wglobal * 16 + r;                // 0..16383
    int tens = gw >> 13;
    int rem = gw & 8191;                      // t*64 + b
    const float* S = ws + (tens ? OFF_S2 : OFF_S1);
    float maxv = Smax[tens];
    float ev = expf(S[(size_t)rem * 64 + lane] + maxv);
    float sum = ev;
    #pragma unroll
    for (int off = 32; off; off >>= 1) sum += __shfl_xor(sum, off);
    float diag = __shfl(ev, rem & 63);
    if (lane == 0) acc += (double)logf(diag / (sum + 1e-5f));
  }
  __shared__ double red[4];
  if (lane == 0) red[wid] = acc;
  __syncthreads();
  if (threadIdx.x == 0)
    ((double*)(ws + OFF_PACC))[blockIdx.x] = red[0] + red[1] + red[2] + red[3];
}

// Kernel 7: reduce 256 per-block partials, finalize loss
__global__ void k_fin(const float* __restrict__ ws, float* __restrict__ out) {
  const double* p = (const double*)(ws + OFF_PACC);
  const int lane = threadIdx.x & 63, wid = threadIdx.x >> 6;
  double v = p[threadIdx.x];
  #pragma unroll
  for (int off = 32; off; off >>= 1) v += __shfl_xor(v, off);
  __shared__ double red[4];
  if (lane == 0) red[wid] = v;
  __syncthreads();
  if (threadIdx.x == 0)
    out[0] = (float)(-(red[0] + red[1] + red[2] + red[3]) / 16384.0);
}

// ---------------------------------------------------------------------------
extern "C" void kernel_launch(void* const* d_in, const int* in_sizes, int n_in,
                              void* d_out, int out_size, void* d_ws, size_t ws_size,
                              hipStream_t stream) {
  const float* A = (const float*)d_in[0];
  const float* V = (const float*)d_in[1];
  const float* E = (const float*)d_in[2];
  float* out = (float*)d_out;
  float* ws  = (float*)d_ws;

  k_sumsq  <<<dim3(4352), dim3(256), 0, stream>>>(A, V, E, ws);
  k_dist   <<<dim3(16, 128, 2), dim3(256), 0, stream>>>(A, V, E, ws);
  k_rowstats<<<dim3(2048, 2), dim3(256), 0, stream>>>(A, V, E, ws, out);
  k_sgemm  <<<dim3(128, 2), dim3(256), 0, stream>>>(ws);
  k_smin   <<<dim3(128, 2), dim3(256), 0, stream>>>(ws);
  k_sfinal <<<dim3(1), dim3(256), 0, stream>>>(ws);
  k_loss   <<<dim3(256), dim3(256), 0, stream>>>(ws);
  k_fin    <<<dim3(1), dim3(256), 0, stream>>>(ws, out);
}